// Round 1
// baseline (76.771 us; speedup 1.0000x reference)
//
#include <hip/hip_runtime.h>
#include <stdint.h>

// SCLinear: out = sc_mat_mac_p(x, W, b, lut, 32)  (forward value of
// lin + stop_grad(p - lin) is exactly p).
// lut[i][j] == floor(i*j/32)  =>  sgn*lut[|a|,|b|] == trunc-toward-zero(a*b/32).
// Exact small-integer arithmetic; no lut memory needed.
//
// R14: TWO-KERNEL SPLIT. The single-kernel publish/poll design (R4-R13)
// paid ~18-25us of intra-kernel cross-XCD visibility latency (sc0/sc1
// uncached publish + 512 polling waves on the same 512B). A kernel
// boundary IS a device-scope release/acquire (runtime flushes/invalidates
// L2 between dispatches), so:
//   k_scales (64 blocks): slice abs-max of {x} and {W,b} -> 64 partial
//       pairs in wsp[0..127], PLAIN stores.
//   k_main (512 blocks): wave 0 reads the 64 pairs (plain cached loads,
//       guaranteed valid -- no poll), reduces, broadcasts scales via LDS;
//       then quantize + exact integer MAC. No speculation, no fixup,
//       no co-residency requirement.
// In-graph kernel->kernel dependency ~2-3us << the handshake it replaces.

#define MROWS 512
#define KDIM  256
#define OCOLS 256

__device__ __forceinline__ void get_scales(float amax, float dmax, int& e2, int& e1) {
    if (amax == 0.0f) amax = 1.0f;
    if (dmax == 0.0f) dmax = 1.0f;
    float q2 = 32.0f / amax;
    float q1 = 32.0f / dmax;
    int f2 = (q2 >= 1073741824.0f) ? 0x40000000 : (int)floorf(q2);
    int f1 = (q1 >= 1073741824.0f) ? 0x40000000 : (int)floorf(q1);
    if (f2 < 1) f2 = 1;
    if (f1 < 1) f1 = 1;
    e2 = 31 - __clz(f2);
    e1 = 31 - __clz(f1);
}

__device__ __forceinline__ float max4(float4 v) {
    return fmaxf(fmaxf(fabsf(v.x), fabsf(v.y)), fmaxf(fabsf(v.z), fabsf(v.w)));
}

// Integer MAC over K with inline W quantization.
__device__ __forceinline__ int mac_loop(const float* __restrict__ W, int o,
                                        const unsigned int* a_sh, float sn1f) {
    const float4* wrow = (const float4*)(W + (size_t)o * KDIM);
    int sum = 0;
    #pragma unroll 8
    for (int kk = 0; kk < KDIM / 4; ++kk) {
        float4 wv = wrow[kk];
        unsigned int ap = a_sh[kk];
        float wfv[4] = {wv.x, wv.y, wv.z, wv.w};
        #pragma unroll
        for (int j = 0; j < 4; ++j) {
            int bv = (int)(wfv[j] * sn1f);
            int av = ((int)(ap << (24 - 8 * j))) >> 24;   // sign-extended byte j
            int s  = av * bv;
            sum += (s + ((s >> 31) & 31)) >> 5;           // == sgn*lut[|av|,|bv|]
        }
    }
    return sum;
}

// ---- kernel 1: partial abs-max reduction (64 blocks x 256 threads) ----
// wsp layout (uint): [2i]=partial amax bits, [2i+1]=partial dmax bits, i<64.
__global__ __launch_bounds__(256)
void k_scales(unsigned int* __restrict__ wsp, const float* __restrict__ x,
              const float* __restrict__ W, const float* __restrict__ b) {
    __shared__ float sm[8];
    const int m = blockIdx.x;
    const int o = threadIdx.x;
    const int wave = o >> 6;

    const float4* xf = (const float4*)x;          // 32768 float4
    const float4* wf = (const float4*)W;          // 16384 float4
    float va = fmaxf(max4(xf[m * 512 + o]), max4(xf[m * 512 + 256 + o]));
    float vd = max4(wf[m * 256 + o]);
    if (m == 0 && o < 64)                         // b: 64 float4
        vd = fmaxf(vd, max4(((const float4*)b)[o]));
    #pragma unroll
    for (int s = 32; s >= 1; s >>= 1) {
        va = fmaxf(va, __shfl_xor(va, s, 64));
        vd = fmaxf(vd, __shfl_xor(vd, s, 64));
    }
    if ((o & 63) == 0) { sm[2 * wave] = va; sm[2 * wave + 1] = vd; }
    __syncthreads();
    if (o == 0) {
        float a = fmaxf(fmaxf(sm[0], sm[2]), fmaxf(sm[4], sm[6]));
        float d = fmaxf(fmaxf(sm[1], sm[3]), fmaxf(sm[5], sm[7]));
        wsp[2 * m]     = __float_as_uint(a);
        wsp[2 * m + 1] = __float_as_uint(d);
    }
}

// ---- kernel 2: scales broadcast + quantize + exact integer MAC ----
__global__ __launch_bounds__(256)
void k_main(const unsigned int* __restrict__ wsp, const float* __restrict__ x,
            const float* __restrict__ W, const float* __restrict__ b,
            float* __restrict__ out) {
    __shared__ unsigned int a_sh[KDIM / 4];
    __shared__ int s_e[2];

    const int m = blockIdx.x;
    const int o = threadIdx.x;

    // Issue independent loads before the scale reduction.
    float bo = b[o];
    float4 xv;
    if (o < KDIM / 4)
        xv = ((const float4*)(x + (size_t)m * KDIM))[o];

    // Wave 0: reduce the 64 partial pairs (valid -- written last dispatch).
    if (o < 64) {
        float va = __uint_as_float(wsp[2 * o]);
        float vd = __uint_as_float(wsp[2 * o + 1]);
        #pragma unroll
        for (int s = 32; s >= 1; s >>= 1) {
            va = fmaxf(va, __shfl_xor(va, s, 64));
            vd = fmaxf(vd, __shfl_xor(vd, s, 64));
        }
        if (o == 0) {
            int e2, e1;
            get_scales(va, vd, e2, e1);
            s_e[0] = e2; s_e[1] = e1;
        }
    }
    __syncthreads();

    const int e2 = s_e[0];
    const int e1 = s_e[1];
    const float sn2f = (float)(1 << e2);
    const float sn1f = (float)(1 << e1);

    // Quantize block's x-row (256 floats) into LDS as packed int8.
    if (o < KDIM / 4) {
        int a0 = (int)(xv.x * sn2f) & 0xFF;
        int a1 = (int)(xv.y * sn2f) & 0xFF;
        int a2 = (int)(xv.z * sn2f) & 0xFF;
        int a3 = (int)(xv.w * sn2f) & 0xFF;
        a_sh[o] = (unsigned int)(a0 | (a1 << 8) | (a2 << 16) | (a3 << 24));
    }
    __syncthreads();

    int sum = mac_loop(W, o, a_sh, sn1f);

    int cc = (int)(bo * sn1f);
    int d  = ((sum + ((sum >> 31) & ((1 << e2) - 1))) >> e2) + cc;
    out[(size_t)m * OCOLS + o] = (float)d * (1.0f / sn1f);
}

extern "C" void kernel_launch(void* const* d_in, const int* in_sizes, int n_in,
                              void* d_out, int out_size, void* d_ws, size_t ws_size,
                              hipStream_t stream) {
    const float* x = (const float*)d_in[0];
    const float* W = (const float*)d_in[1];
    const float* b = (const float*)d_in[2];
    // d_in[3] (lut) unused: lut[i][j] == floor(i*j/32), computed in-ALU.
    float* out = (float*)d_out;
    unsigned int* wsp = (unsigned int*)d_ws;   // 512 B of partial max pairs

    k_scales<<<64,    256, 0, stream>>>(wsp, x, W, b);
    k_main  <<<MROWS, 256, 0, stream>>>(wsp, x, W, b, out);
}